// Round 2
// baseline (65.738 us; speedup 1.0000x reference)
//
#include <hip/hip_runtime.h>
#include <hip/hip_bf16.h>

// LinearCombiner: reference MLP has NO activation -> affine:
//   out = M @ x + c,  M = W3@W2@W1 (8x3072),  c = M2@b1 + W3@b2 + b3 (M2=W3@W2)
// and x[t,u] = [min(a,b)[t]; max(a,b)[t]; user[u]] is separable:
//   out[t,u,o] = P[t,o] + Q[u,o] + c[o].
//
// 6 launches:
//  K1 gemm_partial  : part = W3 @ W2 (32 k-slices, float4, 64-thr blocks)
//  K2 reduce_part   : M2
//  K3 gemm_partial  : part = M2 @ W1  (+1 extra k-slice block computes c)
//  K4 reduce_part   : M
//  K5 proj          : P (256 text blocks) and Q (128 user blocks), fused
//  K6 combine       : out[t,u,:] = P[t]+Q[u]+c

#define HIDN 3072
#define DIM 1024
#define NOUT 8
#define NS 32            // k-slices
#define KPS 96           // HIDN / NS
#define GX 12            // column groups of 256 cols (64 thr * float4)
#define COLS 256
#define TDIM 256
#define UDIM 128

// A: (8, HIDN) row-major; B: (HIDN, HIDN) row-major.
// part[s][o][h] = sum_{k in slice s} A[o,k] * B[k,h]
// When do_bias && blockIdx.y==NS: single block computes c = M2@b1 + W3@b2 + b3.
__global__ __launch_bounds__(64) void gemm_partial(
    const float* __restrict__ A, const float* __restrict__ B,
    float* __restrict__ part,
    const float* __restrict__ M2b, const float* __restrict__ W3b,
    const float* __restrict__ b1, const float* __restrict__ b2,
    const float* __restrict__ b3, float* __restrict__ c, int do_bias) {
    const int s = blockIdx.y;
    const int tid = threadIdx.x;

    if (s == NS) {                       // bias-fold block (only in launch K3)
        if (!do_bias || blockIdx.x != 0) return;
        float acc[NOUT];
#pragma unroll
        for (int o = 0; o < NOUT; ++o) acc[o] = 0.0f;
        for (int k = tid; k < HIDN; k += 64) {
            float vb1 = b1[k], vb2 = b2[k];
#pragma unroll
            for (int o = 0; o < NOUT; ++o)
                acc[o] += M2b[o * HIDN + k] * vb1 + W3b[o * HIDN + k] * vb2;
        }
#pragma unroll
        for (int o = 0; o < NOUT; ++o) {
#pragma unroll
            for (int off = 32; off > 0; off >>= 1)
                acc[o] += __shfl_down(acc[o], off, 64);
        }
        if (tid == 0) {
#pragma unroll
            for (int o = 0; o < NOUT; ++o) c[o] = acc[o] + b3[o];
        }
        return;
    }

    const int h = blockIdx.x * COLS + tid * 4;
    const int k0 = s * KPS;

    __shared__ float As[NOUT][KPS];
    for (int i = tid; i < NOUT * KPS; i += 64)
        As[i / KPS][i % KPS] = A[(i / KPS) * HIDN + k0 + (i % KPS)];
    __syncthreads();

    float4 acc[NOUT];
#pragma unroll
    for (int o = 0; o < NOUT; ++o) acc[o] = make_float4(0.f, 0.f, 0.f, 0.f);

    const float4* Bp = (const float4*)(B + (size_t)k0 * HIDN + h);
#pragma unroll 16
    for (int kk = 0; kk < KPS; ++kk) {
        float4 b = Bp[(size_t)kk * (HIDN / 4)];
#pragma unroll
        for (int o = 0; o < NOUT; ++o) {
            float a = As[o][kk];
            acc[o].x += a * b.x; acc[o].y += a * b.y;
            acc[o].z += a * b.z; acc[o].w += a * b.w;
        }
    }

#pragma unroll
    for (int o = 0; o < NOUT; ++o)
        *(float4*)(part + ((size_t)s * NOUT + o) * HIDN + h) = acc[o];
}

// out[i] = sum_s part[s][i], vectorized float4; 32 independent loads/thread.
__global__ __launch_bounds__(64) void reduce_part(const float* __restrict__ part,
                                                  float* __restrict__ out) {
    const int i4 = blockIdx.x * 64 + threadIdx.x;   // [0, NOUT*HIDN/4)
    const float4* p = (const float4*)part;
    float4 acc = make_float4(0.f, 0.f, 0.f, 0.f);
#pragma unroll 8
    for (int s = 0; s < NS; ++s) {
        float4 v = p[(size_t)s * (NOUT * HIDN / 4) + i4];
        acc.x += v.x; acc.y += v.y; acc.z += v.z; acc.w += v.w;
    }
    ((float4*)out)[i4] = acc;
}

__device__ __forceinline__ float dot4(float4 a, float4 b) {
    return a.x * b.x + a.y * b.y + a.z * b.z + a.w * b.w;
}

// blocks [0,256): P[t,o] = M[o,0:1024].min + M[o,1024:2048].max
// blocks [256,384): Q[u,o] = M[o,2048:3072].user
__global__ __launch_bounds__(128) void proj(const float* __restrict__ ta,
                                            const float* __restrict__ tb,
                                            const float* __restrict__ user,
                                            const float* __restrict__ M,
                                            float* __restrict__ P,
                                            float* __restrict__ Q) {
    const int tid = threadIdx.x;
    const int bid = blockIdx.x;
    float acc[NOUT];
#pragma unroll
    for (int o = 0; o < NOUT; ++o) acc[o] = 0.0f;

    if (bid < TDIM) {
        const int t = bid;
#pragma unroll
        for (int cch = 0; cch < 2; ++cch) {
            const int d = cch * 512 + tid * 4;
            float4 a = *(const float4*)(ta + t * DIM + d);
            float4 b = *(const float4*)(tb + t * DIM + d);
            float4 mn = make_float4(fminf(a.x, b.x), fminf(a.y, b.y),
                                    fminf(a.z, b.z), fminf(a.w, b.w));
            float4 mx = make_float4(fmaxf(a.x, b.x), fmaxf(a.y, b.y),
                                    fmaxf(a.z, b.z), fmaxf(a.w, b.w));
#pragma unroll
            for (int o = 0; o < NOUT; ++o) {
                float4 ml = *(const float4*)(M + o * HIDN + d);
                float4 mh = *(const float4*)(M + o * HIDN + DIM + d);
                acc[o] += dot4(ml, mn) + dot4(mh, mx);
            }
        }
    } else {
        const int u = bid - TDIM;
#pragma unroll
        for (int cch = 0; cch < 2; ++cch) {
            const int d = cch * 512 + tid * 4;
            float4 x = *(const float4*)(user + u * DIM + d);
#pragma unroll
            for (int o = 0; o < NOUT; ++o) {
                float4 m = *(const float4*)(M + o * HIDN + 2 * DIM + d);
                acc[o] += dot4(m, x);
            }
        }
    }

#pragma unroll
    for (int o = 0; o < NOUT; ++o) {
#pragma unroll
        for (int off = 32; off > 0; off >>= 1)
            acc[o] += __shfl_down(acc[o], off, 64);
    }
    __shared__ float red[2][NOUT];
    const int lane = tid & 63, w = tid >> 6;
    if (lane == 0) {
#pragma unroll
        for (int o = 0; o < NOUT; ++o) red[w][o] = acc[o];
    }
    __syncthreads();
    float* dst = (bid < TDIM) ? (P + bid * NOUT) : (Q + (bid - TDIM) * NOUT);
    if (tid < NOUT) dst[tid] = red[0][tid] + red[1][tid];
}

// out[t,u,o] = P[t,o] + Q[u,o] + c[o]
__global__ __launch_bounds__(256) void combine_out(const float* __restrict__ P,
                                                   const float* __restrict__ Q,
                                                   const float* __restrict__ c,
                                                   float4* __restrict__ out) {
    const int idx = blockIdx.x * 256 + threadIdx.x;  // [0, T*U)
    const int t = idx >> 7, u = idx & (UDIM - 1);
    const float4* Pp = (const float4*)(P) + t * 2;
    const float4* Qp = (const float4*)(Q) + u * 2;
    const float4* Cp = (const float4*)(c);
    float4 p0 = Pp[0], p1 = Pp[1];
    float4 q0 = Qp[0], q1 = Qp[1];
    float4 c0 = Cp[0], c1 = Cp[1];
    float4 r0 = {p0.x + q0.x + c0.x, p0.y + q0.y + c0.y,
                 p0.z + q0.z + c0.z, p0.w + q0.w + c0.w};
    float4 r1 = {p1.x + q1.x + c1.x, p1.y + q1.y + c1.y,
                 p1.z + q1.z + c1.z, p1.w + q1.w + c1.w};
    out[idx * 2] = r0;
    out[idx * 2 + 1] = r1;
}

extern "C" void kernel_launch(void* const* d_in, const int* in_sizes, int n_in,
                              void* d_out, int out_size, void* d_ws, size_t ws_size,
                              hipStream_t stream) {
    const float* text_a = (const float*)d_in[0];
    const float* text_b = (const float*)d_in[1];
    const float* user   = (const float*)d_in[2];
    const float* W1 = (const float*)d_in[3];
    const float* b1 = (const float*)d_in[4];
    const float* W2 = (const float*)d_in[5];
    const float* b2 = (const float*)d_in[6];
    const float* W3 = (const float*)d_in[7];
    const float* b3 = (const float*)d_in[8];

    float* ws = (float*)d_ws;
    float* part = ws;                                 // NS*NOUT*HIDN = 786432 floats
    float* M2 = part + (size_t)NS * NOUT * HIDN;      // 24576 floats
    float* M  = M2 + NOUT * HIDN;                     // 24576 floats
    float* c  = M + NOUT * HIDN;                      // 8 floats
    float* P  = c + NOUT;                             // 2048 floats (16B aligned)
    float* Q  = P + TDIM * NOUT;                      // 1024 floats

    // K1: part = W3 @ W2
    gemm_partial<<<dim3(GX, NS), 64, 0, stream>>>(W3, W2, part, M2, W3, b1, b2, b3, c, 0);
    // K2: M2 = reduce(part)
    reduce_part<<<(NOUT * HIDN / 4) / 64, 64, 0, stream>>>(part, M2);
    // K3: part = M2 @ W1 ; extra slice computes c = M2@b1 + W3@b2 + b3
    gemm_partial<<<dim3(GX, NS + 1), 64, 0, stream>>>(M2, W1, part, M2, W3, b1, b2, b3, c, 1);
    // K4: M = reduce(part)
    reduce_part<<<(NOUT * HIDN / 4) / 64, 64, 0, stream>>>(part, M);
    // K5: P, Q
    proj<<<TDIM + UDIM, 128, 0, stream>>>(text_a, text_b, user, M, P, Q);
    // K6: out
    combine_out<<<(TDIM * UDIM) / 256, 256, 0, stream>>>(P, Q, c, (float4*)d_out);
}

// Round 3
// 41.018 us; speedup vs baseline: 1.6027x; 1.6027x over previous
//
#include <hip/hip_runtime.h>
#include <hip/hip_bf16.h>

// LinearCombiner: reference MLP has NO activation -> affine:
//   out = M @ x + c,  M = W3@W2@W1 (8x3072),  c = M2@b1 + W3@b2 + b3 (M2=W3@W2)
// and x[t,u] = [min(a,b)[t]; max(a,b)[t]; user[u]] is separable:
//   out[t,u,o] = P[t,o] + Q[u,o] + c[o].
//
// 6 launches:
//  K1 gemm_partial : part = W3 @ W2   (32 k-slices; 4 waves/block split slice)
//  K2 reduce_part  : M2
//  K3 gemm_partial : part = M2 @ W1   (+extra blockIdx.y==NS computes c)
//  K4 reduce_part  : M
//  K5 proj         : P (256 text blocks) and Q (128 user blocks), fused
//  K6 combine      : out[t,u,:] = P[t]+Q[u]+c

#define HIDN 3072
#define DIM 1024
#define NOUT 8
#define NS 32            // k-slices (partial stays 3 MB)
#define KPS 96           // HIDN / NS rows per slice
#define WK 24            // rows per wave (KPS / 4)
#define GX 12            // column groups of 256 cols
#define TDIM 256
#define UDIM 128

// A: (8, HIDN) row-major; B: (HIDN, HIDN) row-major.
// part[s][o][h] = sum_{k in slice s} A[o,k] * B[k,h]
__global__ __launch_bounds__(256) void gemm_partial(
    const float* __restrict__ A, const float* __restrict__ B,
    float* __restrict__ part,
    const float* __restrict__ b1, const float* __restrict__ b2,
    const float* __restrict__ b3, const float* __restrict__ W3b,
    float* __restrict__ c, int do_bias) {
    const int s = blockIdx.y;
    const int tid = threadIdx.x;
    const int lane = tid & 63, w = tid >> 6;

    __shared__ float As[NOUT * KPS];          // 3 KB
    __shared__ float4 red[4 * NOUT * 64];     // 32 KB, [w][o][lane]
    __shared__ float cred[4][NOUT];

    if (s == NS) {                            // bias-fold block (launch K3 only)
        if (!do_bias || blockIdx.x != 0) return;
        // c[o] = sum_k M2[o,k]*b1[k] + W3[o,k]*b2[k] ; M2 == A here
        float acc[NOUT];
#pragma unroll
        for (int o = 0; o < NOUT; ++o) acc[o] = 0.0f;
        for (int k = tid; k < HIDN; k += 256) {
            float vb1 = b1[k], vb2 = b2[k];
#pragma unroll
            for (int o = 0; o < NOUT; ++o)
                acc[o] += A[o * HIDN + k] * vb1 + W3b[o * HIDN + k] * vb2;
        }
#pragma unroll
        for (int o = 0; o < NOUT; ++o) {
#pragma unroll
            for (int off = 32; off > 0; off >>= 1)
                acc[o] += __shfl_down(acc[o], off, 64);
        }
        if (lane == 0) {
#pragma unroll
            for (int o = 0; o < NOUT; ++o) cred[w][o] = acc[o];
        }
        __syncthreads();
        if (tid < NOUT)
            c[tid] = cred[0][tid] + cred[1][tid] + cred[2][tid] + cred[3][tid] + b3[tid];
        return;
    }

    const int h = blockIdx.x * 256 + lane * 4;   // 64 float4 columns per block
    const int k0 = s * KPS + w * WK;             // this wave's 24 rows

    for (int i = tid; i < NOUT * KPS; i += 256)
        As[i] = A[(i / KPS) * HIDN + s * KPS + (i % KPS)];
    __syncthreads();

    float4 acc[NOUT];
#pragma unroll
    for (int o = 0; o < NOUT; ++o) acc[o] = make_float4(0.f, 0.f, 0.f, 0.f);

    const float4* Bp = (const float4*)(B + (size_t)k0 * HIDN) + (h >> 2);
#pragma unroll 8
    for (int kk = 0; kk < WK; ++kk) {
        float4 b = Bp[(size_t)kk * (HIDN / 4)];
#pragma unroll
        for (int o = 0; o < NOUT; ++o) {
            float a = As[o * KPS + w * WK + kk];
            acc[o].x += a * b.x; acc[o].y += a * b.y;
            acc[o].z += a * b.z; acc[o].w += a * b.w;
        }
    }

    // cross-wave reduce: publish, then wave w sums outputs {2w, 2w+1}
#pragma unroll
    for (int o = 0; o < NOUT; ++o) red[(w * NOUT + o) * 64 + lane] = acc[o];
    __syncthreads();
#pragma unroll
    for (int j = 0; j < 2; ++j) {
        const int o = w * 2 + j;
        float4 v0 = red[(0 * NOUT + o) * 64 + lane];
        float4 v1 = red[(1 * NOUT + o) * 64 + lane];
        float4 v2 = red[(2 * NOUT + o) * 64 + lane];
        float4 v3 = red[(3 * NOUT + o) * 64 + lane];
        float4 r = make_float4(v0.x + v1.x + v2.x + v3.x,
                               v0.y + v1.y + v2.y + v3.y,
                               v0.z + v1.z + v2.z + v3.z,
                               v0.w + v1.w + v2.w + v3.w);
        *(float4*)(part + ((size_t)s * NOUT + o) * HIDN + h) = r;
    }
}

// out[i4] = sum_s part[s][i4]; 4 waves split the 32 slices 8-way each.
__global__ __launch_bounds__(256) void reduce_part(const float* __restrict__ part,
                                                   float* __restrict__ out) {
    const int tid = threadIdx.x, lane = tid & 63, sq = tid >> 6;
    const int i4 = blockIdx.x * 64 + lane;       // [0, NOUT*HIDN/4)
    const float4* p = (const float4*)part;
    float4 acc = make_float4(0.f, 0.f, 0.f, 0.f);
#pragma unroll
    for (int j = 0; j < NS / 4; ++j) {
        float4 v = p[(size_t)(sq * (NS / 4) + j) * (NOUT * HIDN / 4) + i4];
        acc.x += v.x; acc.y += v.y; acc.z += v.z; acc.w += v.w;
    }
    __shared__ float4 red[4 * 64];
    red[sq * 64 + lane] = acc;
    __syncthreads();
    if (sq == 0) {
        float4 a = red[lane], b = red[64 + lane];
        float4 c2 = red[128 + lane], d = red[192 + lane];
        float4 r = make_float4(a.x + b.x + c2.x + d.x, a.y + b.y + c2.y + d.y,
                               a.z + b.z + c2.z + d.z, a.w + b.w + c2.w + d.w);
        ((float4*)out)[i4] = r;
    }
}

__device__ __forceinline__ float dot4(float4 a, float4 b) {
    return a.x * b.x + a.y * b.y + a.z * b.z + a.w * b.w;
}

// blocks [0,256): P[t,o] ; blocks [256,384): Q[u,o]
__global__ __launch_bounds__(256) void proj(const float* __restrict__ ta,
                                            const float* __restrict__ tb,
                                            const float* __restrict__ user,
                                            const float* __restrict__ M,
                                            float* __restrict__ P,
                                            float* __restrict__ Q) {
    const int tid = threadIdx.x;
    const int bid = blockIdx.x;
    const int lane = tid & 63, w = tid >> 6;
    const int d = tid * 4;
    float acc[NOUT];
#pragma unroll
    for (int o = 0; o < NOUT; ++o) acc[o] = 0.0f;

    if (bid < TDIM) {
        const int t = bid;
        float4 a = *(const float4*)(ta + t * DIM + d);
        float4 b = *(const float4*)(tb + t * DIM + d);
        float4 mn = make_float4(fminf(a.x, b.x), fminf(a.y, b.y),
                                fminf(a.z, b.z), fminf(a.w, b.w));
        float4 mx = make_float4(fmaxf(a.x, b.x), fmaxf(a.y, b.y),
                                fmaxf(a.z, b.z), fmaxf(a.w, b.w));
#pragma unroll
        for (int o = 0; o < NOUT; ++o) {
            float4 ml = *(const float4*)(M + o * HIDN + d);
            float4 mh = *(const float4*)(M + o * HIDN + DIM + d);
            acc[o] = dot4(ml, mn) + dot4(mh, mx);
        }
    } else {
        const int u = bid - TDIM;
        float4 x = *(const float4*)(user + u * DIM + d);
#pragma unroll
        for (int o = 0; o < NOUT; ++o) {
            float4 m = *(const float4*)(M + o * HIDN + 2 * DIM + d);
            acc[o] = dot4(m, x);
        }
    }

#pragma unroll
    for (int o = 0; o < NOUT; ++o) {
#pragma unroll
        for (int off = 32; off > 0; off >>= 1)
            acc[o] += __shfl_down(acc[o], off, 64);
    }
    __shared__ float red[4][NOUT];
    if (lane == 0) {
#pragma unroll
        for (int o = 0; o < NOUT; ++o) red[w][o] = acc[o];
    }
    __syncthreads();
    float* dst = (bid < TDIM) ? (P + bid * NOUT) : (Q + (bid - TDIM) * NOUT);
    if (tid < NOUT) dst[tid] = red[0][tid] + red[1][tid] + red[2][tid] + red[3][tid];
}

// out[t,u,o] = P[t,o] + Q[u,o] + c[o]
__global__ __launch_bounds__(256) void combine_out(const float* __restrict__ P,
                                                   const float* __restrict__ Q,
                                                   const float* __restrict__ c,
                                                   float4* __restrict__ out) {
    const int idx = blockIdx.x * 256 + threadIdx.x;  // [0, T*U)
    const int t = idx >> 7, u = idx & (UDIM - 1);
    const float4* Pp = (const float4*)(P) + t * 2;
    const float4* Qp = (const float4*)(Q) + u * 2;
    const float4* Cp = (const float4*)(c);
    float4 p0 = Pp[0], p1 = Pp[1];
    float4 q0 = Qp[0], q1 = Qp[1];
    float4 c0 = Cp[0], c1 = Cp[1];
    float4 r0 = {p0.x + q0.x + c0.x, p0.y + q0.y + c0.y,
                 p0.z + q0.z + c0.z, p0.w + q0.w + c0.w};
    float4 r1 = {p1.x + q1.x + c1.x, p1.y + q1.y + c1.y,
                 p1.z + q1.z + c1.z, p1.w + q1.w + c1.w};
    out[idx * 2] = r0;
    out[idx * 2 + 1] = r1;
}

extern "C" void kernel_launch(void* const* d_in, const int* in_sizes, int n_in,
                              void* d_out, int out_size, void* d_ws, size_t ws_size,
                              hipStream_t stream) {
    const float* text_a = (const float*)d_in[0];
    const float* text_b = (const float*)d_in[1];
    const float* user   = (const float*)d_in[2];
    const float* W1 = (const float*)d_in[3];
    const float* b1 = (const float*)d_in[4];
    const float* W2 = (const float*)d_in[5];
    const float* b2 = (const float*)d_in[6];
    const float* W3 = (const float*)d_in[7];
    const float* b3 = (const float*)d_in[8];

    float* ws = (float*)d_ws;
    float* part = ws;                                 // NS*NOUT*HIDN = 786432 floats
    float* M2 = part + (size_t)NS * NOUT * HIDN;      // 24576 floats
    float* M  = M2 + NOUT * HIDN;                     // 24576 floats
    float* c  = M + NOUT * HIDN;                      // 8 floats
    float* P  = c + NOUT;                             // 2048 floats (16B aligned)
    float* Q  = P + TDIM * NOUT;                      // 1024 floats

    // K1: part = W3 @ W2
    gemm_partial<<<dim3(GX, NS), 256, 0, stream>>>(W3, W2, part, b1, b2, b3, W3, c, 0);
    // K2: M2 = reduce(part)
    reduce_part<<<(NOUT * HIDN / 4) / 64, 256, 0, stream>>>(part, M2);
    // K3: part = M2 @ W1 ; extra slice computes c = M2@b1 + W3@b2 + b3
    gemm_partial<<<dim3(GX, NS + 1), 256, 0, stream>>>(M2, W1, part, b1, b2, b3, W3, c, 1);
    // K4: M = reduce(part)
    reduce_part<<<(NOUT * HIDN / 4) / 64, 256, 0, stream>>>(part, M);
    // K5: P, Q
    proj<<<TDIM + UDIM, 256, 0, stream>>>(text_a, text_b, user, M, P, Q);
    // K6: out
    combine_out<<<(TDIM * UDIM) / 256, 256, 0, stream>>>(P, Q, c, (float4*)d_out);
}